// Round 3
// baseline (390.298 us; speedup 1.0000x reference)
//
#include <hip/hip_runtime.h>
#include <hip/hip_bf16.h>
#include <stdint.h>

// Fused causal self-attention block: qkv GEMM -> flash attention -> proj GEMM.
// B=4 T=2048 E=1024 H=16 HD=64. All GEMM/attn matmuls in bf16 MFMA
// (mfma_f32_16x16x32_bf16), fp32 accumulate.

#define B_  4
#define T_  2048
#define E_  1024
#define H_  16
#define HD_ 64

typedef unsigned short u16;
typedef __bf16 bf16x8 __attribute__((ext_vector_type(8)));
typedef float f32x4 __attribute__((ext_vector_type(4)));

struct alignas(8) us4 { u16 x, y, z, w; };

__device__ __forceinline__ u16 tobf(float f) {
  union { float f; uint32_t u; } x; x.f = f;
  uint32_t r = (x.u + 0x7FFF + ((x.u >> 16) & 1)) >> 16;  // RNE
  return (u16)r;
}

__device__ __forceinline__ void gload_lds16(const void* g, void* l) {
  // global -> LDS direct, 16B per lane (wave-uniform LDS base + lane*16).
  auto gp = reinterpret_cast<const __attribute__((address_space(1))) uint32_t*>(
      reinterpret_cast<uintptr_t>(g));
  auto lp = reinterpret_cast<__attribute__((address_space(3))) uint32_t*>(
      reinterpret_cast<uintptr_t>(l));
  __builtin_amdgcn_global_load_lds(gp, lp, 16, 0, 0);
}

__device__ __forceinline__ bf16x8 ld_frag(const u16* p) {
  return *reinterpret_cast<const bf16x8*>(p);
}

// DPP-based 16-lane all-reduce (pure VALU: quad_perm xor1, xor2, row_ror 4, 8)
#define DPPF(x, ctrl) __uint_as_float((unsigned)__builtin_amdgcn_update_dpp( \
    (int)__float_as_uint(x), (int)__float_as_uint(x), (ctrl), 0xF, 0xF, true))

__device__ __forceinline__ float rmax16(float x) {
  x = fmaxf(x, DPPF(x, 0xB1));   // quad_perm(1,0,3,2)  xor 1
  x = fmaxf(x, DPPF(x, 0x4E));   // quad_perm(2,3,0,1)  xor 2
  x = fmaxf(x, DPPF(x, 0x124));  // row_ror:4
  x = fmaxf(x, DPPF(x, 0x128));  // row_ror:8
  return x;
}
__device__ __forceinline__ float rsum16(float x) {
  x += DPPF(x, 0xB1);
  x += DPPF(x, 0x4E);
  x += DPPF(x, 0x124);
  x += DPPF(x, 0x128);
  return x;
}

// ---------------- conversion kernels ----------------

__global__ void cvt_bf16_kernel(const float* __restrict__ in, u16* __restrict__ out, int n) {
  int i = (blockIdx.x * blockDim.x + threadIdx.x) * 4;
  if (i >= n) return;
  float4 v = *reinterpret_cast<const float4*>(in + i);
  us4 o = { tobf(v.x), tobf(v.y), tobf(v.z), tobf(v.w) };
  *reinterpret_cast<us4*>(out + i) = o;
}

// in: [K][N] f32 row-major -> out: [N][K] bf16 (B^T layout for GEMM)
__global__ void transpose_cvt_kernel(const float* __restrict__ in, u16* __restrict__ out,
                                     int K, int N) {
  __shared__ u16 tile[32][33];
  int n0 = blockIdx.x * 32, k0 = blockIdx.y * 32;
  int tx = threadIdx.x, ty = threadIdx.y;  // (32,8)
#pragma unroll
  for (int i = 0; i < 32; i += 8)
    tile[ty + i][tx] = tobf(in[(size_t)(k0 + ty + i) * N + n0 + tx]);
  __syncthreads();
#pragma unroll
  for (int i = 0; i < 32; i += 8)
    out[(size_t)(n0 + ty + i) * K + k0 + tx] = tile[tx][ty + i];
}

// ---------------- GEMM (m97-style 128x128 tile, BK=32) ----------------

template <int MODE>
__launch_bounds__(256)
__global__ void gemm_kernel(const u16* __restrict__ A, const u16* __restrict__ Bt,
                            const float* __restrict__ bias,
                            u16* __restrict__ qws, u16* __restrict__ kws,
                            u16* __restrict__ vtws, float* __restrict__ out) {
  constexpr int K = 1024, BK = 32;
  __shared__ u16 As[128 * BK];
  __shared__ u16 Bs[128 * BK];
  const int tid = threadIdx.x;
  const int wid = tid >> 6, lane = tid & 63;
  const int wm = wid >> 1, wn = wid & 1;  // 2x2 wave grid, 64x64 per wave
  const int row0 = blockIdx.x * 128, col0 = blockIdx.y * 128;

  f32x4 acc[4][4] = {};

  const int sr = lane >> 2;
  const int sc = (lane & 3) * 8;
  const int lrow = lane & 15;
  const int lkb = (lane >> 4) * 8;

  for (int k0 = 0; k0 < K; k0 += BK) {
#pragma unroll
    for (int c = 0; c < 2; ++c) {
      int chunk = wid * 2 + c;
      int r = chunk * 16 + sr;
      gload_lds16(A + (size_t)(row0 + r) * K + k0 + sc, &As[chunk * 512]);
      gload_lds16(Bt + (size_t)(col0 + r) * K + k0 + sc, &Bs[chunk * 512]);
    }
    __syncthreads();
    bf16x8 af[4], bf[4];
#pragma unroll
    for (int i = 0; i < 4; ++i) {
      af[i] = ld_frag(&As[(wm * 64 + i * 16 + lrow) * BK + lkb]);
      bf[i] = ld_frag(&Bs[(wn * 64 + i * 16 + lrow) * BK + lkb]);
    }
#pragma unroll
    for (int i = 0; i < 4; ++i)
#pragma unroll
      for (int j = 0; j < 4; ++j)
        acc[i][j] = __builtin_amdgcn_mfma_f32_16x16x32_bf16(af[i], bf[j], acc[i][j], 0, 0, 0);
    __syncthreads();
  }

  // C/D layout: col = lane&15, row = (lane>>4)*4 + reg
#pragma unroll
  for (int mi = 0; mi < 4; ++mi) {
#pragma unroll
    for (int ni = 0; ni < 4; ++ni) {
      const int gr0 = row0 + wm * 64 + mi * 16 + (lane >> 4) * 4;
      const int gc = col0 + wn * 64 + ni * 16 + (lane & 15);
      const float bv = bias[gc];
      f32x4 v = acc[mi][ni];
      if constexpr (MODE == 0) {
        const int part = gc >> 10;          // 0=q 1=k 2=v
        const int e = gc & 1023;
        const int h = e >> 6, d = e & 63;
#pragma unroll
        for (int r = 0; r < 4; ++r) {
          const int m = gr0 + r;
          const int b = m >> 11, t = m & 2047;
          const float val = v[r] + bv;
          const size_t bh = (size_t)(b * H_ + h);
          if (part == 0)
            qws[(bh * T_ + t) * HD_ + d] = tobf(val * 0.125f);  // fold 1/sqrt(64)
          else if (part == 1)
            kws[(bh * T_ + t) * HD_ + d] = tobf(val);
          else
            vtws[(bh * HD_ + d) * T_ + t] = tobf(val);          // V transposed
        }
      } else {
#pragma unroll
        for (int r = 0; r < 4; ++r) {
          const int m = gr0 + r;
          out[(size_t)m * E_ + gc] = v[r] + bv;
        }
      }
    }
  }
}

// ---------------- flash attention ----------------
// grid = 1024 blocks x 4 waves. XCD-swizzled so each XCD owns 8 heads
// (K/V footprint 4MB = one L2). Each wave owns TWO mirrored 16-row granules
// (g, 127-g) -> constant work per wave. KV blocks of 64. K software-pipelined
// one block ahead (latency hides under softmax + P-LDS + PV). Softmax via DPP.

__launch_bounds__(256, 4)
__global__ void attn_kernel(const u16* __restrict__ q, const u16* __restrict__ k,
                            const u16* __restrict__ vt, u16* __restrict__ y) {
  __shared__ u16 pt[4][16][72];  // per-wave P tile (16 q-rows x 64 kv, padded)
  const int tid = threadIdx.x, w = tid >> 6, lane = tid & 63;
  // XCD swizzle: 1024 blocks, 8 XCDs -> heads [8x, 8x+8) on XCD x
  const int bid = blockIdx.x;
  const int swz = (bid & 7) * 128 + (bid >> 3);
  const int bh = swz >> 4, blk = swz & 15;
  const int pg = blk * 4 + w;              // 0..63: granule pair id
  const u16* qp = q + (size_t)bh * T_ * HD_;
  const u16* kp = k + (size_t)bh * T_ * HD_;
  const u16* vp = vt + (size_t)bh * HD_ * T_;
  const int b = bh >> 4, h = bh & 15;
  u16* yb = y + (size_t)b * T_ * E_ + h * HD_;
  u16* ptw = &pt[w][0][0];
  const int lc = lane & 15, lk = lane >> 4;

#pragma unroll
  for (int ph = 0; ph < 2; ++ph) {
    const int g = ph ? (127 - pg) : pg;    // mirrored pair -> constant work
    const int qb = g * 16;

    const bf16x8 aq0 = ld_frag(qp + (size_t)(qb + lc) * HD_ + lk * 8);
    const bf16x8 aq1 = ld_frag(qp + (size_t)(qb + lc) * HD_ + 32 + lk * 8);

    f32x4 o[4] = {};
    float mr[4], lr[4];
#pragma unroll
    for (int r = 0; r < 4; ++r) { mr[r] = -1e30f; lr[r] = 0.f; }

    // K prefetch: kc = current block's K frags, kn = next block's
    bf16x8 kc[4][2], kn[4][2];
#pragma unroll
    for (int n = 0; n < 4; ++n) {
      kc[n][0] = ld_frag(kp + (size_t)(n * 16 + lc) * HD_ + lk * 8);
      kc[n][1] = ld_frag(kp + (size_t)(n * 16 + lc) * HD_ + 32 + lk * 8);
    }

    for (int kv0 = 0; kv0 < qb + 16; kv0 += 64) {
      // S = Q K^T : 16 q-rows x 64 kv-cols (K already in registers)
      f32x4 s[4] = {};
#pragma unroll
      for (int n = 0; n < 4; ++n) {
        s[n] = __builtin_amdgcn_mfma_f32_16x16x32_bf16(aq0, kc[n][0], s[n], 0, 0, 0);
        s[n] = __builtin_amdgcn_mfma_f32_16x16x32_bf16(aq1, kc[n][1], s[n], 0, 0, 0);
      }
      // issue V loads (consumed by PV at end of iteration)
      bf16x8 vf[4][2];
#pragma unroll
      for (int n = 0; n < 4; ++n)
#pragma unroll
        for (int hh = 0; hh < 2; ++hh)
          vf[n][hh] = ld_frag(vp + (size_t)(n * 16 + lc) * T_ + kv0 + hh * 32 + lk * 8);
      // issue next K block loads (row clamped in-bounds; unused on last iter)
      {
        const int kvn = kv0 + 64;
#pragma unroll
        for (int n = 0; n < 4; ++n) {
          int row = kvn + n * 16 + lc; row = row < 2047 ? row : 2047;
          kn[n][0] = ld_frag(kp + (size_t)row * HD_ + lk * 8);
          kn[n][1] = ld_frag(kp + (size_t)row * HD_ + 32 + lk * 8);
        }
      }
      // causal mask (only blocks crossing the diagonal)
      if (kv0 + 63 > qb) {
#pragma unroll
        for (int n = 0; n < 4; ++n) {
          const int kv = kv0 + n * 16 + lc;
#pragma unroll
          for (int r = 0; r < 4; ++r)
            if (kv > qb + lk * 4 + r) s[n][r] = -1e30f;
        }
      }
      // online softmax; row r lives on the 16-lane group (cols = lane&15)
      float al[4];
#pragma unroll
      for (int r = 0; r < 4; ++r) {
        float pm = fmaxf(fmaxf(s[0][r], s[1][r]), fmaxf(s[2][r], s[3][r]));
        pm = rmax16(pm);
        const float mn = fmaxf(mr[r], pm);
        al[r] = __expf(mr[r] - mn);
        mr[r] = mn;
      }
      float rs[4] = {0.f, 0.f, 0.f, 0.f};
#pragma unroll
      for (int n = 0; n < 4; ++n)
#pragma unroll
        for (int r = 0; r < 4; ++r) {
          const float p = __expf(s[n][r] - mr[r]);
          s[n][r] = p;
          rs[r] += p;
        }
#pragma unroll
      for (int r = 0; r < 4; ++r) {
        rs[r] = rsum16(rs[r]);
        lr[r] = lr[r] * al[r] + rs[r];
      }
#pragma unroll
      for (int n = 0; n < 4; ++n)
#pragma unroll
        for (int r = 0; r < 4; ++r)
          o[n][r] *= al[r];
      // P (C-layout) -> LDS -> A-layout fragments (per-wave region, no barrier)
#pragma unroll
      for (int n = 0; n < 4; ++n)
#pragma unroll
        for (int r = 0; r < 4; ++r)
          pt[w][lk * 4 + r][n * 16 + lc] = tobf(s[n][r]);
      const bf16x8 pa0 = ld_frag(&ptw[lc * 72 + lk * 8]);
      const bf16x8 pa1 = ld_frag(&ptw[lc * 72 + 32 + lk * 8]);
      // O += P V
#pragma unroll
      for (int n = 0; n < 4; ++n) {
        o[n] = __builtin_amdgcn_mfma_f32_16x16x32_bf16(pa0, vf[n][0], o[n], 0, 0, 0);
        o[n] = __builtin_amdgcn_mfma_f32_16x16x32_bf16(pa1, vf[n][1], o[n], 0, 0, 0);
      }
      // rotate prefetch buffers (SSA rename, no real moves expected)
#pragma unroll
      for (int n = 0; n < 4; ++n) {
        kc[n][0] = kn[n][0];
        kc[n][1] = kn[n][1];
      }
    }

    float invl[4];
#pragma unroll
    for (int r = 0; r < 4; ++r) invl[r] = 1.f / lr[r];
#pragma unroll
    for (int n = 0; n < 4; ++n)
#pragma unroll
      for (int r = 0; r < 4; ++r) {
        const int t = qb + lk * 4 + r;
        yb[(size_t)t * E_ + n * 16 + lc] = tobf(o[n][r] * invl[r]);
      }
  }
}

// ---------------- launch ----------------

extern "C" void kernel_launch(void* const* d_in, const int* in_sizes, int n_in,
                              void* d_out, int out_size, void* d_ws, size_t ws_size,
                              hipStream_t stream) {
  const float* x  = (const float*)d_in[0];
  const float* Wa = (const float*)d_in[1];
  const float* ba = (const float*)d_in[2];
  const float* Wp = (const float*)d_in[3];
  const float* bp = (const float*)d_in[4];
  float* out = (float*)d_out;

  u16* ws   = (u16*)d_ws;
  u16* xb   = ws;                                  // 8M  (x bf16; later y bf16)
  u16* waT  = xb  + (size_t)8 * 1024 * 1024;       // 3M  (W_attn^T bf16)
  u16* wpT  = waT + (size_t)3 * 1024 * 1024;       // 1M  (W_proj^T bf16)
  u16* qws  = wpT + (size_t)1024 * 1024;           // 8M  q [B,H,T,HD]
  u16* kws  = qws + (size_t)8 * 1024 * 1024;       // 8M  k [B,H,T,HD]
  u16* vtws = kws + (size_t)8 * 1024 * 1024;       // 8M  v^T [B,H,HD,T]
  u16* yws  = xb;                                  // alias

  cvt_bf16_kernel<<<dim3(8192), dim3(256), 0, stream>>>(x, xb, 8 * 1024 * 1024);
  transpose_cvt_kernel<<<dim3(96, 32), dim3(32, 8), 0, stream>>>(Wa, waT, 1024, 3072);
  transpose_cvt_kernel<<<dim3(32, 32), dim3(32, 8), 0, stream>>>(Wp, wpT, 1024, 1024);

  gemm_kernel<0><<<dim3(64, 24), dim3(256), 0, stream>>>(xb, waT, ba, qws, kws, vtws, nullptr);
  attn_kernel<<<dim3(1024), dim3(256), 0, stream>>>(qws, kws, vtws, yws);
  gemm_kernel<1><<<dim3(64, 8), dim3(256), 0, stream>>>(yws, wpT, bp, nullptr, nullptr, nullptr, out);
}

// Round 4
// 227.605 us; speedup vs baseline: 1.7148x; 1.7148x over previous
//
#include <hip/hip_runtime.h>
#include <hip/hip_bf16.h>
#include <stdint.h>

// Fused causal self-attention block: qkv GEMM -> flash attention -> proj GEMM.
// B=4 T=2048 E=1024 H=16 HD=64. All GEMM/attn matmuls in bf16 MFMA
// (mfma_f32_16x16x32_bf16), fp32 accumulate.

#define B_  4
#define T_  2048
#define E_  1024
#define H_  16
#define HD_ 64

typedef unsigned short u16;
typedef __bf16 bf16x8 __attribute__((ext_vector_type(8)));
typedef float f32x4 __attribute__((ext_vector_type(4)));

struct alignas(8) us4 { u16 x, y, z, w; };

__device__ __forceinline__ u16 tobf(float f) {
  union { float f; uint32_t u; } x; x.f = f;
  uint32_t r = (x.u + 0x7FFF + ((x.u >> 16) & 1)) >> 16;  // RNE
  return (u16)r;
}

__device__ __forceinline__ void gload_lds16(const void* g, void* l) {
  // global -> LDS direct, 16B per lane (wave-uniform LDS base + lane*16).
  auto gp = reinterpret_cast<const __attribute__((address_space(1))) uint32_t*>(
      reinterpret_cast<uintptr_t>(g));
  auto lp = reinterpret_cast<__attribute__((address_space(3))) uint32_t*>(
      reinterpret_cast<uintptr_t>(l));
  __builtin_amdgcn_global_load_lds(gp, lp, 16, 0, 0);
}

__device__ __forceinline__ bf16x8 ld_frag(const u16* p) {
  return *reinterpret_cast<const bf16x8*>(p);
}

// DPP-based 16-lane all-reduce (pure VALU: quad_perm xor1, xor2, row_ror 4, 8)
#define DPPF(x, ctrl) __uint_as_float((unsigned)__builtin_amdgcn_update_dpp( \
    (int)__float_as_uint(x), (int)__float_as_uint(x), (ctrl), 0xF, 0xF, true))

__device__ __forceinline__ float rmax16(float x) {
  x = fmaxf(x, DPPF(x, 0xB1));   // quad_perm xor1
  x = fmaxf(x, DPPF(x, 0x4E));   // quad_perm xor2
  x = fmaxf(x, DPPF(x, 0x124));  // row_ror:4
  x = fmaxf(x, DPPF(x, 0x128));  // row_ror:8
  return x;
}
__device__ __forceinline__ float rsum16(float x) {
  x += DPPF(x, 0xB1);
  x += DPPF(x, 0x4E);
  x += DPPF(x, 0x124);
  x += DPPF(x, 0x128);
  return x;
}

// ---------------- conversion kernels ----------------

__global__ void cvt_bf16_kernel(const float* __restrict__ in, u16* __restrict__ out, int n) {
  int i = (blockIdx.x * blockDim.x + threadIdx.x) * 4;
  if (i >= n) return;
  float4 v = *reinterpret_cast<const float4*>(in + i);
  us4 o = { tobf(v.x), tobf(v.y), tobf(v.z), tobf(v.w) };
  *reinterpret_cast<us4*>(out + i) = o;
}

// in: [K][N] f32 row-major -> out: [N][K] bf16 (B^T layout for GEMM)
__global__ void transpose_cvt_kernel(const float* __restrict__ in, u16* __restrict__ out,
                                     int K, int N) {
  __shared__ u16 tile[32][33];
  int n0 = blockIdx.x * 32, k0 = blockIdx.y * 32;
  int tx = threadIdx.x, ty = threadIdx.y;  // (32,8)
#pragma unroll
  for (int i = 0; i < 32; i += 8)
    tile[ty + i][tx] = tobf(in[(size_t)(k0 + ty + i) * N + n0 + tx]);
  __syncthreads();
#pragma unroll
  for (int i = 0; i < 32; i += 8)
    out[(size_t)(n0 + ty + i) * K + k0 + tx] = tile[tx][ty + i];
}

// ---------------- GEMM (m97-style 128x128 tile, BK=32) ----------------

template <int MODE>
__launch_bounds__(256)
__global__ void gemm_kernel(const u16* __restrict__ A, const u16* __restrict__ Bt,
                            const float* __restrict__ bias,
                            u16* __restrict__ qws, u16* __restrict__ kws,
                            u16* __restrict__ vtws, float* __restrict__ out) {
  constexpr int K = 1024, BK = 32;
  __shared__ u16 As[128 * BK];
  __shared__ u16 Bs[128 * BK];
  const int tid = threadIdx.x;
  const int wid = tid >> 6, lane = tid & 63;
  const int wm = wid >> 1, wn = wid & 1;  // 2x2 wave grid, 64x64 per wave
  const int row0 = blockIdx.x * 128, col0 = blockIdx.y * 128;

  f32x4 acc[4][4] = {};

  const int sr = lane >> 2;
  const int sc = (lane & 3) * 8;
  const int lrow = lane & 15;
  const int lkb = (lane >> 4) * 8;

  for (int k0 = 0; k0 < K; k0 += BK) {
#pragma unroll
    for (int c = 0; c < 2; ++c) {
      int chunk = wid * 2 + c;
      int r = chunk * 16 + sr;
      gload_lds16(A + (size_t)(row0 + r) * K + k0 + sc, &As[chunk * 512]);
      gload_lds16(Bt + (size_t)(col0 + r) * K + k0 + sc, &Bs[chunk * 512]);
    }
    __syncthreads();
    bf16x8 af[4], bf[4];
#pragma unroll
    for (int i = 0; i < 4; ++i) {
      af[i] = ld_frag(&As[(wm * 64 + i * 16 + lrow) * BK + lkb]);
      bf[i] = ld_frag(&Bs[(wn * 64 + i * 16 + lrow) * BK + lkb]);
    }
#pragma unroll
    for (int i = 0; i < 4; ++i)
#pragma unroll
      for (int j = 0; j < 4; ++j)
        acc[i][j] = __builtin_amdgcn_mfma_f32_16x16x32_bf16(af[i], bf[j], acc[i][j], 0, 0, 0);
    __syncthreads();
  }

  // C/D layout: col = lane&15, row = (lane>>4)*4 + reg
#pragma unroll
  for (int mi = 0; mi < 4; ++mi) {
#pragma unroll
    for (int ni = 0; ni < 4; ++ni) {
      const int gr0 = row0 + wm * 64 + mi * 16 + (lane >> 4) * 4;
      const int gc = col0 + wn * 64 + ni * 16 + (lane & 15);
      const float bv = bias[gc];
      f32x4 v = acc[mi][ni];
      if constexpr (MODE == 0) {
        const int part = gc >> 10;          // 0=q 1=k 2=v
        const int e = gc & 1023;
        const int h = e >> 6, d = e & 63;
#pragma unroll
        for (int r = 0; r < 4; ++r) {
          const int m = gr0 + r;
          const int b = m >> 11, t = m & 2047;
          const float val = v[r] + bv;
          const size_t bh = (size_t)(b * H_ + h);
          if (part == 0)
            // fold 1/sqrt(64) * log2(e): softmax done in exp2 domain
            qws[(bh * T_ + t) * HD_ + d] = tobf(val * 0.1803368801f);
          else if (part == 1)
            kws[(bh * T_ + t) * HD_ + d] = tobf(val);
          else
            vtws[(bh * HD_ + d) * T_ + t] = tobf(val);          // V transposed
        }
      } else {
#pragma unroll
        for (int r = 0; r < 4; ++r) {
          const int m = gr0 + r;
          out[(size_t)m * E_ + gc] = v[r] + bv;
        }
      }
    }
  }
}

// ---------------- flash attention (shared-KV LDS, 8 waves) ----------------
// grid = 256 blocks x 512 threads. Block handles head bh, mirror-paired
// Q-tiles (j, 7-j) of 256 rows -> constant work. Wave w owns 32 Q rows
// (Q + O in registers). Per KV-64 step: K tile [64kv][64hd] and V^T tile
// [64d][64kv] staged to LDS (double-buffered, global_load_lds w16, each wave
// stages 1KB of each). LDS tiles XOR-swizzled (slot ^= row&7, 16B slots):
// linear gload dest + inverse-permuted global source + same XOR on ds_read
// (T21). Softmax in exp2 domain (log2e folded into Q scale).

__launch_bounds__(512, 2)
__global__ void attn_kernel(const u16* __restrict__ q, const u16* __restrict__ k,
                            const u16* __restrict__ vt, u16* __restrict__ y) {
  __shared__ u16 kl[2][64 * 64];   // [buf][kvrow][hd] swizzled
  __shared__ u16 vl[2][64 * 64];   // [buf][d][kv] swizzled
  __shared__ u16 pt[8][32][72];    // per-wave P tile (padded)
  const int tid = threadIdx.x, w = tid >> 6, lane = tid & 63;
  const int bid = blockIdx.x;
  const int bh = bid >> 2, jp = bid & 3;   // head, tile-pair
  const u16* qp = q + (size_t)bh * T_ * HD_;
  const u16* kp = k + (size_t)bh * T_ * HD_;
  const u16* vp = vt + (size_t)bh * HD_ * T_;
  const int b = bh >> 4, h = bh & 15;
  u16* yb = y + (size_t)b * T_ * E_ + h * HD_;
  u16* ptw = &pt[w][0][0];
  const int lc = lane & 15, lk = lane >> 4;
  const int srow = lane >> 3;      // 0..7: row within this wave's 8-row group
  const int sslot = lane & 7;      // 16B slot within 128B row
  const int sco = ((sslot ^ srow) * 8);  // inverse-swizzled source elem offset
  const int rdm = (lc & 7) * 8;    // read-side XOR mask (elems)

#pragma unroll
  for (int ph = 0; ph < 2; ++ph) {
    const int j = ph ? (7 - jp) : jp;
    const int t0 = j * 256;
    const int qb = t0 + w * 32;              // this wave's first Q row
    const int nblk = (t0 + 256) >> 6;        // KV blocks to process

    bf16x8 aq[2][2];
#pragma unroll
    for (int m = 0; m < 2; ++m)
#pragma unroll
      for (int sl = 0; sl < 2; ++sl)
        aq[m][sl] = ld_frag(qp + (size_t)(qb + m * 16 + lc) * HD_ + sl * 32 + lk * 8);

    f32x4 o[2][4] = {};
    float mr[2][4], lr[2][4];
#pragma unroll
    for (int m = 0; m < 2; ++m)
#pragma unroll
      for (int r = 0; r < 4; ++r) { mr[m][r] = -1e30f; lr[m][r] = 0.f; }

    // prologue: stage KV block 0 into buf 0
    gload_lds16(kp + (size_t)(8 * w + srow) * HD_ + sco, &kl[0][w * 512]);
    gload_lds16(vp + (size_t)(8 * w + srow) * T_ + sco, &vl[0][w * 512]);
    __syncthreads();

    int buf = 0;
    for (int kb = 0; kb < nblk; ++kb) {
      const int kv0 = kb * 64;
      if (kb + 1 < nblk) {  // stage next block into other buffer
        const int kvn = kv0 + 64;
        gload_lds16(kp + (size_t)(kvn + 8 * w + srow) * HD_ + sco, &kl[buf ^ 1][w * 512]);
        gload_lds16(vp + (size_t)(8 * w + srow) * T_ + kvn + sco, &vl[buf ^ 1][w * 512]);
      }
      if (kv0 < qb + 32) {  // wave-uniform causal skip
        // K frags from LDS (swizzled read)
        bf16x8 kf[4][2];
#pragma unroll
        for (int n = 0; n < 4; ++n)
#pragma unroll
          for (int sl = 0; sl < 2; ++sl)
            kf[n][sl] = ld_frag(&kl[buf][(n * 16 + lc) * 64 + ((sl * 32 + lk * 8) ^ rdm)]);
        // S = Q K^T : 32 q-rows x 64 kv
        f32x4 s[2][4] = {};
#pragma unroll
        for (int m = 0; m < 2; ++m)
#pragma unroll
          for (int n = 0; n < 4; ++n) {
            s[m][n] = __builtin_amdgcn_mfma_f32_16x16x32_bf16(aq[m][0], kf[n][0], s[m][n], 0, 0, 0);
            s[m][n] = __builtin_amdgcn_mfma_f32_16x16x32_bf16(aq[m][1], kf[n][1], s[m][n], 0, 0, 0);
          }
        // V frags (issue early; consumed by PV)
        bf16x8 vf[4][2];
#pragma unroll
        for (int n = 0; n < 4; ++n)
#pragma unroll
          for (int ks = 0; ks < 2; ++ks)
            vf[n][ks] = ld_frag(&vl[buf][(n * 16 + lc) * 64 + ((ks * 32 + lk * 8) ^ rdm)]);
        // causal mask
        if (kv0 + 63 > qb) {
#pragma unroll
          for (int m = 0; m < 2; ++m)
#pragma unroll
            for (int n = 0; n < 4; ++n) {
              const int kv = kv0 + n * 16 + lc;
#pragma unroll
              for (int r = 0; r < 4; ++r)
                if (kv > qb + m * 16 + lk * 4 + r) s[m][n][r] = -1e30f;
            }
        }
        // online softmax (exp2 domain)
        float al[2][4];
#pragma unroll
        for (int m = 0; m < 2; ++m)
#pragma unroll
          for (int r = 0; r < 4; ++r) {
            float pm = fmaxf(fmaxf(s[m][0][r], s[m][1][r]), fmaxf(s[m][2][r], s[m][3][r]));
            pm = rmax16(pm);
            const float mn = fmaxf(mr[m][r], pm);
            al[m][r] = exp2f(mr[m][r] - mn);
            mr[m][r] = mn;
          }
        float rs[2][4] = {};
#pragma unroll
        for (int m = 0; m < 2; ++m)
#pragma unroll
          for (int n = 0; n < 4; ++n)
#pragma unroll
            for (int r = 0; r < 4; ++r) {
              const float p = exp2f(s[m][n][r] - mr[m][r]);
              s[m][n][r] = p;
              rs[m][r] += p;
            }
#pragma unroll
        for (int m = 0; m < 2; ++m)
#pragma unroll
          for (int r = 0; r < 4; ++r) {
            lr[m][r] = lr[m][r] * al[m][r] + rsum16(rs[m][r]);
          }
#pragma unroll
        for (int m = 0; m < 2; ++m)
#pragma unroll
          for (int n = 0; n < 4; ++n)
#pragma unroll
            for (int r = 0; r < 4; ++r)
              o[m][n][r] *= al[m][r];
        // P (C-layout) -> LDS -> A-layout frags (per-wave region, no barrier)
#pragma unroll
        for (int m = 0; m < 2; ++m)
#pragma unroll
          for (int n = 0; n < 4; ++n)
#pragma unroll
            for (int r = 0; r < 4; ++r)
              pt[w][m * 16 + lk * 4 + r][n * 16 + lc] = tobf(s[m][n][r]);
        bf16x8 pa[2][2];
#pragma unroll
        for (int m = 0; m < 2; ++m)
#pragma unroll
          for (int ks = 0; ks < 2; ++ks)
            pa[m][ks] = ld_frag(&ptw[(m * 16 + lc) * 72 + ks * 32 + lk * 8]);
        // O += P V
#pragma unroll
        for (int m = 0; m < 2; ++m)
#pragma unroll
          for (int n = 0; n < 4; ++n) {
            o[m][n] = __builtin_amdgcn_mfma_f32_16x16x32_bf16(pa[m][0], vf[n][0], o[m][n], 0, 0, 0);
            o[m][n] = __builtin_amdgcn_mfma_f32_16x16x32_bf16(pa[m][1], vf[n][1], o[m][n], 0, 0, 0);
          }
      }
      __syncthreads();
      buf ^= 1;
    }

    float invl[2][4];
#pragma unroll
    for (int m = 0; m < 2; ++m)
#pragma unroll
      for (int r = 0; r < 4; ++r) invl[m][r] = 1.f / lr[m][r];
#pragma unroll
    for (int m = 0; m < 2; ++m)
#pragma unroll
      for (int n = 0; n < 4; ++n)
#pragma unroll
        for (int r = 0; r < 4; ++r) {
          const int t = qb + m * 16 + lk * 4 + r;
          yb[(size_t)t * E_ + n * 16 + lc] = tobf(o[m][n][r] * invl[m][r]);
        }
  }
}

// ---------------- launch ----------------

extern "C" void kernel_launch(void* const* d_in, const int* in_sizes, int n_in,
                              void* d_out, int out_size, void* d_ws, size_t ws_size,
                              hipStream_t stream) {
  const float* x  = (const float*)d_in[0];
  const float* Wa = (const float*)d_in[1];
  const float* ba = (const float*)d_in[2];
  const float* Wp = (const float*)d_in[3];
  const float* bp = (const float*)d_in[4];
  float* out = (float*)d_out;

  u16* ws   = (u16*)d_ws;
  u16* xb   = ws;                                  // 8M  (x bf16; later y bf16)
  u16* waT  = xb  + (size_t)8 * 1024 * 1024;       // 3M  (W_attn^T bf16)
  u16* wpT  = waT + (size_t)3 * 1024 * 1024;       // 1M  (W_proj^T bf16)
  u16* qws  = wpT + (size_t)1024 * 1024;           // 8M  q [B,H,T,HD]
  u16* kws  = qws + (size_t)8 * 1024 * 1024;       // 8M  k [B,H,T,HD]
  u16* vtws = kws + (size_t)8 * 1024 * 1024;       // 8M  v^T [B,H,HD,T]
  u16* yws  = xb;                                  // alias

  cvt_bf16_kernel<<<dim3(8192), dim3(256), 0, stream>>>(x, xb, 8 * 1024 * 1024);
  transpose_cvt_kernel<<<dim3(96, 32), dim3(32, 8), 0, stream>>>(Wa, waT, 1024, 3072);
  transpose_cvt_kernel<<<dim3(32, 32), dim3(32, 8), 0, stream>>>(Wp, wpT, 1024, 1024);

  gemm_kernel<0><<<dim3(64, 24), dim3(256), 0, stream>>>(xb, waT, ba, qws, kws, vtws, nullptr);
  attn_kernel<<<dim3(256), dim3(512), 0, stream>>>(qws, kws, vtws, yws);
  gemm_kernel<1><<<dim3(64, 8), dim3(256), 0, stream>>>(yws, wpT, bp, nullptr, nullptr, nullptr, out);
}

// Round 5
// 223.374 us; speedup vs baseline: 1.7473x; 1.0189x over previous
//
#include <hip/hip_runtime.h>
#include <hip/hip_bf16.h>
#include <stdint.h>

// Fused causal self-attention block: qkv GEMM -> flash attention -> proj GEMM.
// B=4 T=2048 E=1024 H=16 HD=64. All GEMM/attn matmuls in bf16 MFMA
// (mfma_f32_16x16x32_bf16), fp32 accumulate.

#define B_  4
#define T_  2048
#define E_  1024
#define H_  16
#define HD_ 64

typedef unsigned short u16;
typedef __bf16 bf16x8 __attribute__((ext_vector_type(8)));
typedef float f32x4 __attribute__((ext_vector_type(4)));

struct alignas(8) us4 { u16 x, y, z, w; };

// native bf16 convert (compiler emits v_cvt_pk_bf16_f32; RNE) — NOT hand-rolled
__device__ __forceinline__ u16 tobf(float f) {
  union { __bf16 h; u16 u; } c;
  c.h = (__bf16)f;
  return c.u;
}

__device__ __forceinline__ void gload_lds16(const void* g, void* l) {
  // global -> LDS direct, 16B per lane (wave-uniform LDS base + lane*16).
  auto gp = reinterpret_cast<const __attribute__((address_space(1))) uint32_t*>(
      reinterpret_cast<uintptr_t>(g));
  auto lp = reinterpret_cast<__attribute__((address_space(3))) uint32_t*>(
      reinterpret_cast<uintptr_t>(l));
  __builtin_amdgcn_global_load_lds(gp, lp, 16, 0, 0);
}

__device__ __forceinline__ bf16x8 ld_frag(const u16* p) {
  return *reinterpret_cast<const bf16x8*>(p);
}

// DPP-based 16-lane all-reduce (pure VALU: quad_perm xor1, xor2, row_ror 4, 8)
#define DPPF(x, ctrl) __uint_as_float((unsigned)__builtin_amdgcn_update_dpp( \
    (int)__float_as_uint(x), (int)__float_as_uint(x), (ctrl), 0xF, 0xF, true))

__device__ __forceinline__ float rmax16(float x) {
  x = fmaxf(x, DPPF(x, 0xB1));   // quad_perm xor1
  x = fmaxf(x, DPPF(x, 0x4E));   // quad_perm xor2
  x = fmaxf(x, DPPF(x, 0x124));  // row_ror:4
  x = fmaxf(x, DPPF(x, 0x128));  // row_ror:8
  return x;
}
__device__ __forceinline__ float rsum16(float x) {
  x += DPPF(x, 0xB1);
  x += DPPF(x, 0x4E);
  x += DPPF(x, 0x124);
  x += DPPF(x, 0x128);
  return x;
}

// ---------------- conversion kernels ----------------

__global__ void cvt_bf16_kernel(const float* __restrict__ in, u16* __restrict__ out, int n) {
  int i = (blockIdx.x * blockDim.x + threadIdx.x) * 4;
  if (i >= n) return;
  float4 v = *reinterpret_cast<const float4*>(in + i);
  us4 o = { tobf(v.x), tobf(v.y), tobf(v.z), tobf(v.w) };
  *reinterpret_cast<us4*>(out + i) = o;
}

// in: [K][N] f32 row-major -> out: [N][K] bf16 (B^T layout for GEMM)
__global__ void transpose_cvt_kernel(const float* __restrict__ in, u16* __restrict__ out,
                                     int K, int N) {
  __shared__ u16 tile[32][33];
  int n0 = blockIdx.x * 32, k0 = blockIdx.y * 32;
  int tx = threadIdx.x, ty = threadIdx.y;  // (32,8)
#pragma unroll
  for (int i = 0; i < 32; i += 8)
    tile[ty + i][tx] = tobf(in[(size_t)(k0 + ty + i) * N + n0 + tx]);
  __syncthreads();
#pragma unroll
  for (int i = 0; i < 32; i += 8)
    out[(size_t)(n0 + ty + i) * K + k0 + tx] = tile[tx][ty + i];
}

// ---------------- GEMM (m97-style 128x128 tile, BK=32) ----------------

template <int MODE>
__launch_bounds__(256)
__global__ void gemm_kernel(const u16* __restrict__ A, const u16* __restrict__ Bt,
                            const float* __restrict__ bias,
                            u16* __restrict__ qws, u16* __restrict__ kws,
                            u16* __restrict__ vtws, float* __restrict__ out) {
  constexpr int K = 1024, BK = 32;
  __shared__ u16 As[128 * BK];
  __shared__ u16 Bs[128 * BK];
  const int tid = threadIdx.x;
  const int wid = tid >> 6, lane = tid & 63;
  const int wm = wid >> 1, wn = wid & 1;  // 2x2 wave grid, 64x64 per wave
  const int row0 = blockIdx.x * 128, col0 = blockIdx.y * 128;

  f32x4 acc[4][4] = {};

  const int sr = lane >> 2;
  const int sc = (lane & 3) * 8;
  const int lrow = lane & 15;
  const int lkb = (lane >> 4) * 8;

  for (int k0 = 0; k0 < K; k0 += BK) {
#pragma unroll
    for (int c = 0; c < 2; ++c) {
      int chunk = wid * 2 + c;
      int r = chunk * 16 + sr;
      gload_lds16(A + (size_t)(row0 + r) * K + k0 + sc, &As[chunk * 512]);
      gload_lds16(Bt + (size_t)(col0 + r) * K + k0 + sc, &Bs[chunk * 512]);
    }
    __syncthreads();
    bf16x8 af[4], bf[4];
#pragma unroll
    for (int i = 0; i < 4; ++i) {
      af[i] = ld_frag(&As[(wm * 64 + i * 16 + lrow) * BK + lkb]);
      bf[i] = ld_frag(&Bs[(wn * 64 + i * 16 + lrow) * BK + lkb]);
    }
#pragma unroll
    for (int i = 0; i < 4; ++i)
#pragma unroll
      for (int j = 0; j < 4; ++j)
        acc[i][j] = __builtin_amdgcn_mfma_f32_16x16x32_bf16(af[i], bf[j], acc[i][j], 0, 0, 0);
    __syncthreads();
  }

  // C/D layout: col = lane&15, row = (lane>>4)*4 + reg
#pragma unroll
  for (int mi = 0; mi < 4; ++mi) {
#pragma unroll
    for (int ni = 0; ni < 4; ++ni) {
      const int gr0 = row0 + wm * 64 + mi * 16 + (lane >> 4) * 4;
      const int gc = col0 + wn * 64 + ni * 16 + (lane & 15);
      const float bv = bias[gc];
      f32x4 v = acc[mi][ni];
      if constexpr (MODE == 0) {
        const int part = gc >> 10;          // 0=q 1=k 2=v
        const int e = gc & 1023;
        const int h = e >> 6, d = e & 63;
#pragma unroll
        for (int r = 0; r < 4; ++r) {
          const int m = gr0 + r;
          const int b = m >> 11, t = m & 2047;
          const float val = v[r] + bv;
          const size_t bh = (size_t)(b * H_ + h);
          if (part == 0)
            // fold 1/sqrt(64) * log2(e): softmax done in exp2 domain
            qws[(bh * T_ + t) * HD_ + d] = tobf(val * 0.1803368801f);
          else if (part == 1)
            kws[(bh * T_ + t) * HD_ + d] = tobf(val);
          else
            vtws[(bh * HD_ + d) * T_ + t] = tobf(val);          // V transposed
        }
      } else {
#pragma unroll
        for (int r = 0; r < 4; ++r) {
          const int m = gr0 + r;
          out[(size_t)m * E_ + gc] = v[r] + bv;
        }
      }
    }
  }
}

// ---------------- flash attention (shared-KV LDS, 8 waves) ----------------
// grid = 256 blocks x 512 threads. Block handles head bh, mirror-paired
// Q-tiles (j, 7-j) of 256 rows -> constant work. Wave w owns 32 Q rows
// (Q + O in registers). Per KV-64 step: K tile [64kv][64hd] and V^T tile
// [64d][64kv] staged to LDS (double-buffered, global_load_lds w16). LDS tiles
// XOR-swizzled (slot ^= row&7, 16B slots, T21). Softmax in exp2 domain with
// T13 defer-max; T5 setprio around MFMA clusters.

__launch_bounds__(512, 2)
__global__ void attn_kernel(const u16* __restrict__ q, const u16* __restrict__ k,
                            const u16* __restrict__ vt, u16* __restrict__ y) {
  __shared__ u16 kl[2][64 * 64];   // [buf][kvrow][hd] swizzled
  __shared__ u16 vl[2][64 * 64];   // [buf][d][kv] swizzled
  __shared__ u16 pt[8][32][72];    // per-wave P tile (padded)
  const int tid = threadIdx.x, w = tid >> 6, lane = tid & 63;
  const int bid = blockIdx.x;
  const int bh = bid >> 2, jp = bid & 3;   // head, tile-pair
  const u16* qp = q + (size_t)bh * T_ * HD_;
  const u16* kp = k + (size_t)bh * T_ * HD_;
  const u16* vp = vt + (size_t)bh * HD_ * T_;
  const int b = bh >> 4, h = bh & 15;
  u16* yb = y + (size_t)b * T_ * E_ + h * HD_;
  u16* ptw = &pt[w][0][0];
  const int lc = lane & 15, lk = lane >> 4;
  const int srow = lane >> 3;      // 0..7: row within this wave's 8-row group
  const int sslot = lane & 7;      // 16B slot within 128B row
  const int sco = ((sslot ^ srow) * 8);  // inverse-swizzled source elem offset
  const int rdm = (lc & 7) * 8;    // read-side XOR mask (elems)

#pragma unroll
  for (int ph = 0; ph < 2; ++ph) {
    const int j = ph ? (7 - jp) : jp;
    const int t0 = j * 256;
    const int qb = t0 + w * 32;              // this wave's first Q row
    const int nblk = (t0 + 256) >> 6;        // KV blocks to process

    bf16x8 aq[2][2];
#pragma unroll
    for (int m = 0; m < 2; ++m)
#pragma unroll
      for (int sl = 0; sl < 2; ++sl)
        aq[m][sl] = ld_frag(qp + (size_t)(qb + m * 16 + lc) * HD_ + sl * 32 + lk * 8);

    f32x4 o[2][4] = {};
    float mr[2][4], lr[2][4];
#pragma unroll
    for (int m = 0; m < 2; ++m)
#pragma unroll
      for (int r = 0; r < 4; ++r) { mr[m][r] = -1e30f; lr[m][r] = 0.f; }

    // prologue: stage KV block 0 into buf 0
    gload_lds16(kp + (size_t)(8 * w + srow) * HD_ + sco, &kl[0][w * 512]);
    gload_lds16(vp + (size_t)(8 * w + srow) * T_ + sco, &vl[0][w * 512]);
    __syncthreads();

    int buf = 0;
    for (int kb = 0; kb < nblk; ++kb) {
      const int kv0 = kb * 64;
      if (kb + 1 < nblk) {  // stage next block into other buffer
        const int kvn = kv0 + 64;
        gload_lds16(kp + (size_t)(kvn + 8 * w + srow) * HD_ + sco, &kl[buf ^ 1][w * 512]);
        gload_lds16(vp + (size_t)(8 * w + srow) * T_ + kvn + sco, &vl[buf ^ 1][w * 512]);
      }
      if (kv0 < qb + 32) {  // wave-uniform causal skip
        // K frags from LDS (swizzled read)
        bf16x8 kf[4][2];
#pragma unroll
        for (int n = 0; n < 4; ++n)
#pragma unroll
          for (int sl = 0; sl < 2; ++sl)
            kf[n][sl] = ld_frag(&kl[buf][(n * 16 + lc) * 64 + ((sl * 32 + lk * 8) ^ rdm)]);
        // S = Q K^T : 32 q-rows x 64 kv
        f32x4 s[2][4] = {};
        __builtin_amdgcn_s_setprio(1);
#pragma unroll
        for (int m = 0; m < 2; ++m)
#pragma unroll
          for (int n = 0; n < 4; ++n) {
            s[m][n] = __builtin_amdgcn_mfma_f32_16x16x32_bf16(aq[m][0], kf[n][0], s[m][n], 0, 0, 0);
            s[m][n] = __builtin_amdgcn_mfma_f32_16x16x32_bf16(aq[m][1], kf[n][1], s[m][n], 0, 0, 0);
          }
        __builtin_amdgcn_s_setprio(0);
        // V frags (issue early; consumed by PV)
        bf16x8 vf[4][2];
#pragma unroll
        for (int n = 0; n < 4; ++n)
#pragma unroll
          for (int ks = 0; ks < 2; ++ks)
            vf[n][ks] = ld_frag(&vl[buf][(n * 16 + lc) * 64 + ((ks * 32 + lk * 8) ^ rdm)]);
        // causal mask
        if (kv0 + 63 > qb) {
#pragma unroll
          for (int m = 0; m < 2; ++m)
#pragma unroll
            for (int n = 0; n < 4; ++n) {
              const int kv = kv0 + n * 16 + lc;
#pragma unroll
              for (int r = 0; r < 4; ++r)
                if (kv > qb + m * 16 + lk * 4 + r) s[m][n][r] = -1e30f;
            }
        }
        // online softmax (exp2 domain) with deferred rescale (T13)
        float pm[2][4];
        int need = 0;
#pragma unroll
        for (int m = 0; m < 2; ++m)
#pragma unroll
          for (int r = 0; r < 4; ++r) {
            float v = fmaxf(fmaxf(s[m][0][r], s[m][1][r]), fmaxf(s[m][2][r], s[m][3][r]));
            v = rmax16(v);
            pm[m][r] = v;
            need |= (v - mr[m][r] > 8.f) ? 1 : 0;
          }
        if (__any(need)) {
          float al[2][4];
#pragma unroll
          for (int m = 0; m < 2; ++m)
#pragma unroll
            for (int r = 0; r < 4; ++r) {
              const float mn = fmaxf(mr[m][r], pm[m][r]);
              al[m][r] = exp2f(mr[m][r] - mn);
              mr[m][r] = mn;
              lr[m][r] *= al[m][r];
            }
#pragma unroll
          for (int m = 0; m < 2; ++m)
#pragma unroll
            for (int n = 0; n < 4; ++n)
#pragma unroll
              for (int r = 0; r < 4; ++r)
                o[m][n][r] *= al[m][r];
        }
        float rs[2][4] = {};
#pragma unroll
        for (int m = 0; m < 2; ++m)
#pragma unroll
          for (int n = 0; n < 4; ++n)
#pragma unroll
            for (int r = 0; r < 4; ++r) {
              const float p = exp2f(s[m][n][r] - mr[m][r]);
              s[m][n][r] = p;
              rs[m][r] += p;
            }
#pragma unroll
        for (int m = 0; m < 2; ++m)
#pragma unroll
          for (int r = 0; r < 4; ++r)
            lr[m][r] += rsum16(rs[m][r]);
        // P (C-layout) -> LDS -> A-layout frags (per-wave region, no barrier)
#pragma unroll
        for (int m = 0; m < 2; ++m)
#pragma unroll
          for (int n = 0; n < 4; ++n)
#pragma unroll
            for (int r = 0; r < 4; ++r)
              pt[w][m * 16 + lk * 4 + r][n * 16 + lc] = tobf(s[m][n][r]);
        bf16x8 pa[2][2];
#pragma unroll
        for (int m = 0; m < 2; ++m)
#pragma unroll
          for (int ks = 0; ks < 2; ++ks)
            pa[m][ks] = ld_frag(&ptw[(m * 16 + lc) * 72 + ks * 32 + lk * 8]);
        // O += P V
        __builtin_amdgcn_s_setprio(1);
#pragma unroll
        for (int m = 0; m < 2; ++m)
#pragma unroll
          for (int n = 0; n < 4; ++n) {
            o[m][n] = __builtin_amdgcn_mfma_f32_16x16x32_bf16(pa[m][0], vf[n][0], o[m][n], 0, 0, 0);
            o[m][n] = __builtin_amdgcn_mfma_f32_16x16x32_bf16(pa[m][1], vf[n][1], o[m][n], 0, 0, 0);
          }
        __builtin_amdgcn_s_setprio(0);
      }
      __syncthreads();
      buf ^= 1;
    }

    float invl[2][4];
#pragma unroll
    for (int m = 0; m < 2; ++m)
#pragma unroll
      for (int r = 0; r < 4; ++r) invl[m][r] = 1.f / lr[m][r];
#pragma unroll
    for (int m = 0; m < 2; ++m)
#pragma unroll
      for (int n = 0; n < 4; ++n)
#pragma unroll
        for (int r = 0; r < 4; ++r) {
          const int t = qb + m * 16 + lk * 4 + r;
          yb[(size_t)t * E_ + n * 16 + lc] = tobf(o[m][n][r] * invl[m][r]);
        }
  }
}

// ---------------- launch ----------------

extern "C" void kernel_launch(void* const* d_in, const int* in_sizes, int n_in,
                              void* d_out, int out_size, void* d_ws, size_t ws_size,
                              hipStream_t stream) {
  const float* x  = (const float*)d_in[0];
  const float* Wa = (const float*)d_in[1];
  const float* ba = (const float*)d_in[2];
  const float* Wp = (const float*)d_in[3];
  const float* bp = (const float*)d_in[4];
  float* out = (float*)d_out;

  u16* ws   = (u16*)d_ws;
  u16* xb   = ws;                                  // 8M  (x bf16; later y bf16)
  u16* waT  = xb  + (size_t)8 * 1024 * 1024;       // 3M  (W_attn^T bf16)
  u16* wpT  = waT + (size_t)3 * 1024 * 1024;       // 1M  (W_proj^T bf16)
  u16* qws  = wpT + (size_t)1024 * 1024;           // 8M  q [B,H,T,HD]
  u16* kws  = qws + (size_t)8 * 1024 * 1024;       // 8M  k [B,H,T,HD]
  u16* vtws = kws + (size_t)8 * 1024 * 1024;       // 8M  v^T [B,H,HD,T]
  u16* yws  = xb;                                  // alias

  cvt_bf16_kernel<<<dim3(8192), dim3(256), 0, stream>>>(x, xb, 8 * 1024 * 1024);
  transpose_cvt_kernel<<<dim3(96, 32), dim3(32, 8), 0, stream>>>(Wa, waT, 1024, 3072);
  transpose_cvt_kernel<<<dim3(32, 32), dim3(32, 8), 0, stream>>>(Wp, wpT, 1024, 1024);

  gemm_kernel<0><<<dim3(64, 24), dim3(256), 0, stream>>>(xb, waT, ba, qws, kws, vtws, nullptr);
  attn_kernel<<<dim3(256), dim3(512), 0, stream>>>(qws, kws, vtws, yws);
  gemm_kernel<1><<<dim3(64, 8), dim3(256), 0, stream>>>(yws, wpT, bp, nullptr, nullptr, nullptr, out);
}